// Round 4
// baseline (727.786 us; speedup 1.0000x reference)
//
#include <hip/hip_runtime.h>
#include <cstddef>
#include <cstdint>

#define NND 100000
#define NED 1600000
#define NEP (NED + NND)

typedef short v8s __attribute__((ext_vector_type(8)));
typedef float v4f __attribute__((ext_vector_type(4)));

// ---------------- bf16 split helpers ----------------
__device__ __forceinline__ uint32_t f32_to_bf16_rne(float x) {
    uint32_t u = __builtin_bit_cast(uint32_t, x);
    return (u + 0x7fffu + ((u >> 16) & 1u)) >> 16;
}
__device__ __forceinline__ float bf16bits_to_f32(uint32_t b) {
    return __builtin_bit_cast(float, b << 16);
}
// pack f32 -> (hi bf16 in low16, lo bf16 in high16)
__device__ __forceinline__ uint32_t pack_split(float x) {
    uint32_t hi = f32_to_bf16_rne(x);
    float resid = x - bf16bits_to_f32(hi);
    uint32_t lo = f32_to_bf16_rne(resid);
    return hi | (lo << 16);
}

// ---------------- edge dtype detection ----------------
__global__ void k_detect(const long long* __restrict__ ei, int* __restrict__ flag) {
    __shared__ int ok;
    if (threadIdx.x == 0) ok = 1;
    __syncthreads();
    for (int i = threadIdx.x; i < 2048; i += blockDim.x) {
        long long v = ei[i];
        if (v < 0 || v >= NND) ok = 0;
    }
    __syncthreads();
    if (threadIdx.x == 0) *flag = ok;
}

__device__ __forceinline__ void load_edge(const void* ei, int is64, int e, int& src, int& dst) {
    if (e >= NED) { src = dst = e - NED; return; }  // self-loop
    if (is64) {
        const long long* p = (const long long*)ei;
        src = (int)p[e];
        dst = (int)p[NED + e];
    } else {
        const int* p = (const int*)ei;
        src = p[e];
        dst = p[NED + e];
    }
}

// ---------------- degree / norm ----------------
__global__ void k_deg(const void* __restrict__ ei, const int* __restrict__ flag,
                      int* __restrict__ deg) {
    int e = blockIdx.x * 256 + threadIdx.x;
    if (e >= NEP) return;
    int s, d;
    load_edge(ei, *flag, e, s, d);
    atomicAdd(&deg[d], 1);
}

__global__ void k_dinv(const int* __restrict__ deg, float* __restrict__ dinv) {
    int n = blockIdx.x * 256 + threadIdx.x;
    if (n >= NND) return;
    int d = deg[n];
    if (d < 1) d = 1;
    dinv[n] = 1.0f / sqrtf((float)d);
}

// ---------------- exclusive scan of deg -> row_off ----------------
__global__ __launch_bounds__(1024) void k_scan1(const int* __restrict__ deg,
                                                int* __restrict__ row_off,
                                                int* __restrict__ bsum) {
    __shared__ int sh[1024];
    int i = blockIdx.x * 1024 + threadIdx.x;
    int v = (i < NND) ? deg[i] : 0;
    sh[threadIdx.x] = v;
    __syncthreads();
    for (int off = 1; off < 1024; off <<= 1) {
        int t = 0;
        if ((int)threadIdx.x >= off) t = sh[threadIdx.x - off];
        __syncthreads();
        sh[threadIdx.x] += t;
        __syncthreads();
    }
    if (i < NND) row_off[i] = sh[threadIdx.x] - v;  // exclusive
    if (threadIdx.x == 1023) bsum[blockIdx.x] = sh[1023];
}

__global__ void k_scan2(int* __restrict__ bsum, int nb) {
    __shared__ int sh[128];
    int t = threadIdx.x;
    int orig = (t < nb) ? bsum[t] : 0;
    sh[t] = orig;
    __syncthreads();
    for (int off = 1; off < 128; off <<= 1) {
        int v = 0;
        if (t >= off) v = sh[t - off];
        __syncthreads();
        sh[t] += v;
        __syncthreads();
    }
    if (t < nb) bsum[t] = sh[t] - orig;  // exclusive block offsets
}

__global__ void k_scan3(int* __restrict__ row_off, const int* __restrict__ bsum) {
    int i = blockIdx.x * 256 + threadIdx.x;
    if (i < NND) row_off[i] += bsum[i >> 10];
    if (i == 0) row_off[NND] = NEP;
}

// ---------------- CSR fill (col = src, sorted by dst) ----------------
__global__ void k_fill(const void* __restrict__ ei, const int* __restrict__ flag,
                       const int* __restrict__ row_off, int* __restrict__ cursor,
                       int* __restrict__ col) {
    int e = blockIdx.x * 256 + threadIdx.x;
    if (e >= NEP) return;
    int s, d;
    load_edge(ei, *flag, e, s, d);
    int pos = row_off[d] + atomicAdd(&cursor[d], 1);
    col[pos] = s;
}

// ---------------- W prep: transpose + split into planar bf16 hi/lo ----------------
__global__ void k_wprep(const float* __restrict__ W, unsigned short* __restrict__ wth,
                        unsigned short* __restrict__ wtl, int K, int N) {
    int i = blockIdx.x * 256 + threadIdx.x;
    if (i >= K * N) return;
    int k = i / N, n = i % N;
    float x = W[i];
    uint32_t hi = f32_to_bf16_rne(x);
    float resid = x - bf16bits_to_f32(hi);
    uint32_t lo = f32_to_bf16_rne(resid);
    wth[(size_t)n * K + k] = (unsigned short)hi;
    wtl[(size_t)n * K + k] = (unsigned short)lo;
}

// ---------------- aggregation ----------------
// out[n] = dinv[n] * sum_{src in N(n)} dinv[src] * in[src]  (+bias, relu)
// Input always f32 row-major. If OUT_SPLIT, writes (hi,lo) bf16-split u32 elems.
template <int C, bool BIAS, bool RELU, bool OUT_SPLIT>
__global__ __launch_bounds__(C) void k_agg(const float* __restrict__ in, float* __restrict__ out,
                      const int* __restrict__ row_off, const int* __restrict__ col,
                      const float* __restrict__ dinv, const float* __restrict__ bias) {
    constexpr int LPG = C / 4;  // lanes per group (float4 each)
    constexpr int NG = 4;       // edge groups
    constexpr int MAXE = 256;   // staged edges per chunk
    __shared__ int sidx[MAXE];
    __shared__ float snrm[MAXE];
    __shared__ float4 red[NG][LPG];

    const int n = blockIdx.x;
    const int t = threadIdx.x;
    const int g = t / LPG;
    const int l = t % LPG;
    const int s = row_off[n], e = row_off[n + 1];
    const float4* __restrict__ in4 = (const float4*)in;

    float4 a0 = make_float4(0.f, 0.f, 0.f, 0.f);
    float4 a1 = make_float4(0.f, 0.f, 0.f, 0.f);
    float4 a2 = make_float4(0.f, 0.f, 0.f, 0.f);
    float4 a3 = make_float4(0.f, 0.f, 0.f, 0.f);

    for (int base = s; base < e; base += MAXE) {
        const int cnt = min(e - base, MAXE);
        for (int i = t; i < cnt; i += C) {
            int c = col[base + i];
            sidx[i] = c;
            snrm[i] = dinv[c];
        }
        __syncthreads();

        int k = g;
        for (; k + 3 * NG < cnt; k += 4 * NG) {
            int s0 = sidx[k];
            int s1 = sidx[k + NG];
            int s2 = sidx[k + 2 * NG];
            int s3 = sidx[k + 3 * NG];
            float d0 = snrm[k];
            float d1 = snrm[k + NG];
            float d2 = snrm[k + 2 * NG];
            float d3 = snrm[k + 3 * NG];
            float4 v0 = in4[(size_t)s0 * LPG + l];
            float4 v1 = in4[(size_t)s1 * LPG + l];
            float4 v2 = in4[(size_t)s2 * LPG + l];
            float4 v3 = in4[(size_t)s3 * LPG + l];
            a0.x = fmaf(d0, v0.x, a0.x); a0.y = fmaf(d0, v0.y, a0.y);
            a0.z = fmaf(d0, v0.z, a0.z); a0.w = fmaf(d0, v0.w, a0.w);
            a1.x = fmaf(d1, v1.x, a1.x); a1.y = fmaf(d1, v1.y, a1.y);
            a1.z = fmaf(d1, v1.z, a1.z); a1.w = fmaf(d1, v1.w, a1.w);
            a2.x = fmaf(d2, v2.x, a2.x); a2.y = fmaf(d2, v2.y, a2.y);
            a2.z = fmaf(d2, v2.z, a2.z); a2.w = fmaf(d2, v2.w, a2.w);
            a3.x = fmaf(d3, v3.x, a3.x); a3.y = fmaf(d3, v3.y, a3.y);
            a3.z = fmaf(d3, v3.z, a3.z); a3.w = fmaf(d3, v3.w, a3.w);
        }
        for (; k < cnt; k += NG) {
            int s0 = sidx[k];
            float d0 = snrm[k];
            float4 v0 = in4[(size_t)s0 * LPG + l];
            a0.x = fmaf(d0, v0.x, a0.x); a0.y = fmaf(d0, v0.y, a0.y);
            a0.z = fmaf(d0, v0.z, a0.z); a0.w = fmaf(d0, v0.w, a0.w);
        }
        __syncthreads();  // protect sidx/snrm before next chunk
    }

    a0.x += a1.x + a2.x + a3.x;
    a0.y += a1.y + a2.y + a3.y;
    a0.z += a1.z + a2.z + a3.z;
    a0.w += a1.w + a2.w + a3.w;
    red[g][l] = a0;
    __syncthreads();
    if (g == 0) {
        float4 r = red[0][l];
        float4 r1 = red[1][l];
        float4 r2 = red[2][l];
        float4 r3 = red[3][l];
        r.x += r1.x + r2.x + r3.x;
        r.y += r1.y + r2.y + r3.y;
        r.z += r1.z + r2.z + r3.z;
        r.w += r1.w + r2.w + r3.w;
        float dn = dinv[n];
        r.x *= dn; r.y *= dn; r.z *= dn; r.w *= dn;
        if constexpr (BIAS) {
            float4 bv = ((const float4*)bias)[l];
            r.x += bv.x; r.y += bv.y; r.z += bv.z; r.w += bv.w;
        }
        if constexpr (RELU) {
            r.x = fmaxf(r.x, 0.f); r.y = fmaxf(r.y, 0.f);
            r.z = fmaxf(r.z, 0.f); r.w = fmaxf(r.w, 0.f);
        }
        if constexpr (OUT_SPLIT) {
            uint4 o;
            o.x = pack_split(r.x); o.y = pack_split(r.y);
            o.z = pack_split(r.z); o.w = pack_split(r.w);
            ((uint4*)out)[(size_t)n * LPG + l] = o;
        } else {
            ((float4*)out)[(size_t)n * LPG + l] = r;
        }
    }
}

// ---------------- MFMA split-bf16 GEMM ----------------
// C[M,N] = act[M,K] @ W[K,N], act stored split-interleaved (u32 = hi|lo<<16),
// W pre-transposed planar (wth/wtl = Wt[n][k] bf16 bits).
// Trick: D = Wt_frag (MFMA-A) x Act_frag (MFMA-B) gives C^T tiles; both operand
// frags are 16B-contiguous global loads; D lanes hold 4 consecutive n -> 16B store.
// No LDS, no barriers. 3 MFMAs per tile: AhBh + AhBl + AlBh (err ~2^-16).
template <int K, int N, int MT, bool BIAS, bool OUT_SPLIT>
__global__ __launch_bounds__(256) void k_mgemm(
    const uint32_t* __restrict__ act, const unsigned short* __restrict__ wth,
    const unsigned short* __restrict__ wtl, const float* __restrict__ bias,
    void* __restrict__ outp, int nrows)
{
    constexpr int NT = N / 16;
    const int lane = threadIdx.x & 63;
    const int wave = threadIdx.x >> 6;
    const int l15 = lane & 15;
    const int lq = lane >> 4;  // 0..3
    const int row0 = (blockIdx.x * 4 + wave) * (MT * 16);

    v4f acc[MT][NT];
#pragma unroll
    for (int i = 0; i < MT; ++i)
#pragma unroll
        for (int j = 0; j < NT; ++j) acc[i][j] = (v4f){0.f, 0.f, 0.f, 0.f};

    const int woff0 = l15 * K + lq * 8;

#pragma unroll
    for (int kc = 0; kc < K; kc += 32) {
        v8s ah[MT], al[MT];
#pragma unroll
        for (int mt = 0; mt < MT; ++mt) {
            int r = row0 + mt * 16 + l15;
            if (r > nrows - 1) r = nrows - 1;
            const uint32_t* p = act + (size_t)r * K + kc + lq * 8;
            uint4 q0 = *(const uint4*)p;
            uint4 q1 = *(const uint4*)(p + 4);
            union { uint32_t u[4]; v8s v; } h, lo;
            h.u[0]  = (q0.x & 0xffffu) | (q0.y << 16);
            lo.u[0] = (q0.x >> 16)     | (q0.y & 0xffff0000u);
            h.u[1]  = (q0.z & 0xffffu) | (q0.w << 16);
            lo.u[1] = (q0.z >> 16)     | (q0.w & 0xffff0000u);
            h.u[2]  = (q1.x & 0xffffu) | (q1.y << 16);
            lo.u[2] = (q1.x >> 16)     | (q1.y & 0xffff0000u);
            h.u[3]  = (q1.z & 0xffffu) | (q1.w << 16);
            lo.u[3] = (q1.z >> 16)     | (q1.w & 0xffff0000u);
            ah[mt] = h.v;
            al[mt] = lo.v;
        }
#pragma unroll
        for (int nt = 0; nt < NT; ++nt) {
            const v8s bh = *(const v8s*)(wth + (size_t)nt * 16 * K + woff0 + kc);
            const v8s bl = *(const v8s*)(wtl + (size_t)nt * 16 * K + woff0 + kc);
#pragma unroll
            for (int mt = 0; mt < MT; ++mt) {
                acc[mt][nt] = __builtin_amdgcn_mfma_f32_16x16x32_bf16(bh, ah[mt], acc[mt][nt], 0, 0, 0);
                acc[mt][nt] = __builtin_amdgcn_mfma_f32_16x16x32_bf16(bh, al[mt], acc[mt][nt], 0, 0, 0);
                acc[mt][nt] = __builtin_amdgcn_mfma_f32_16x16x32_bf16(bl, ah[mt], acc[mt][nt], 0, 0, 0);
            }
        }
    }

#pragma unroll
    for (int mt = 0; mt < MT; ++mt) {
        int m = row0 + mt * 16 + l15;
        if (m >= nrows) continue;
#pragma unroll
        for (int nt = 0; nt < NT; ++nt) {
            int nc = nt * 16 + lq * 4;
            v4f v = acc[mt][nt];
            if constexpr (BIAS) {
                float4 bv = *(const float4*)(bias + nc);
                v[0] += bv.x; v[1] += bv.y; v[2] += bv.z; v[3] += bv.w;
            }
            if constexpr (OUT_SPLIT) {
                uint4 o;
                o.x = pack_split(v[0]); o.y = pack_split(v[1]);
                o.z = pack_split(v[2]); o.w = pack_split(v[3]);
                *(uint4*)((uint32_t*)outp + (size_t)m * N + nc) = o;
            } else {
                float4 o = make_float4(v[0], v[1], v[2], v[3]);
                *(float4*)((float*)outp + (size_t)m * N + nc) = o;
            }
        }
    }
}

// ---------------- host ----------------
extern "C" void kernel_launch(void* const* d_in, const int* in_sizes, int n_in,
                              void* d_out, int out_size, void* d_ws, size_t ws_size,
                              hipStream_t stream) {
    const float* x = (const float*)d_in[0];
    const void* ei = d_in[1];
    const float* W1 = (const float*)d_in[2];
    const float* b1 = (const float*)d_in[3];
    const float* W2 = (const float*)d_in[4];
    const float* b2 = (const float*)d_in[5];
    const float* W3 = (const float*)d_in[6];
    const float* b3 = (const float*)d_in[7];
    float* out = (float*)d_out;

    char* ws = (char*)d_ws;
    size_t off = 0;
    auto alloc = [&](size_t bytes) -> void* {
        void* p = ws + off;
        off = (off + bytes + 255) & ~(size_t)255;
        return p;
    };

    int* flag = (int*)alloc(sizeof(int));
    int* deg = (int*)alloc((size_t)NND * 4);
    int* cursor = (int*)alloc((size_t)NND * 4);
    int* row_off = (int*)alloc((size_t)(NND + 1) * 4);
    int* bsum = (int*)alloc(512);
    float* dinv = (float*)alloc((size_t)NND * 4);
    int* col = (int*)alloc((size_t)NEP * 4);
    unsigned short* wt1h = (unsigned short*)alloc((size_t)128 * 256 * 2);
    unsigned short* wt1l = (unsigned short*)alloc((size_t)128 * 256 * 2);
    unsigned short* wt2h = (unsigned short*)alloc((size_t)256 * 128 * 2);
    unsigned short* wt2l = (unsigned short*)alloc((size_t)256 * 128 * 2);
    unsigned short* wt3h = (unsigned short*)alloc((size_t)128 * 64 * 2);
    unsigned short* wt3l = (unsigned short*)alloc((size_t)128 * 64 * 2);
    uint32_t* AX = (uint32_t*)alloc((size_t)NND * 128 * 4);  // split; aliased as H2 (f32) later
    uint32_t* A1 = (uint32_t*)alloc((size_t)NND * 256 * 4);  // split; aliased as H3 (f32) later
    uint32_t* A2 = (uint32_t*)alloc((size_t)NND * 128 * 4);  // split
    float* H2 = (float*)AX;  // AX dead after gemm1
    float* H3 = (float*)A1;  // A1 dead after gemm2

    hipMemsetAsync(deg, 0, (size_t)NND * 4, stream);
    hipMemsetAsync(cursor, 0, (size_t)NND * 4, stream);

    k_detect<<<1, 256, 0, stream>>>((const long long*)ei, flag);

    const int gE = (NEP + 255) / 256;
    const int gN = (NND + 255) / 256;
    k_deg<<<gE, 256, 0, stream>>>(ei, flag, deg);
    k_dinv<<<gN, 256, 0, stream>>>(deg, dinv);

    const int NB = (NND + 1023) / 1024;  // 98
    k_scan1<<<NB, 1024, 0, stream>>>(deg, row_off, bsum);
    k_scan2<<<1, 128, 0, stream>>>(bsum, NB);
    k_scan3<<<gN, 256, 0, stream>>>(row_off, bsum);

    k_fill<<<gE, 256, 0, stream>>>(ei, flag, row_off, cursor, col);

    k_wprep<<<(128 * 256 + 255) / 256, 256, 0, stream>>>(W1, wt1h, wt1l, 128, 256);
    k_wprep<<<(256 * 128 + 255) / 256, 256, 0, stream>>>(W2, wt2h, wt2l, 256, 128);
    k_wprep<<<(128 * 64 + 255) / 256, 256, 0, stream>>>(W3, wt3h, wt3l, 128, 64);

    // L1: AX = Ahat @ X (split out) ; A1 = AX @ W1 + b1 (split out)
    k_agg<128, false, false, true><<<NND, 128, 0, stream>>>(x, (float*)AX, row_off, col, dinv, nullptr);
    k_mgemm<128, 256, 1, true, true><<<(NND + 63) / 64, 256, 0, stream>>>(AX, wt1h, wt1l, b1, A1, NND);

    // L2: H2 = A1 @ W2 (f32 out) ; A2 = relu(Ahat @ H2 + b2) (split out)
    k_mgemm<256, 128, 2, false, false><<<(NND + 127) / 128, 256, 0, stream>>>(A1, wt2h, wt2l, nullptr, H2, NND);
    k_agg<128, true, true, true><<<NND, 128, 0, stream>>>(H2, (float*)A2, row_off, col, dinv, b2);

    // L3: H3 = A2 @ W3 (f32 out) ; out = Ahat @ H3 + b3
    k_mgemm<128, 64, 2, false, false><<<(NND + 127) / 128, 256, 0, stream>>>(A2, wt3h, wt3l, nullptr, H3, NND);
    k_agg<64, true, false, false><<<NND, 64, 0, stream>>>(H3, out, row_off, col, dinv, b3);
}